// Round 8
// baseline (1462.150 us; speedup 1.0000x reference)
//
#include <hip/hip_runtime.h>

#define NB 128
#define TT 512
#define TAG 256
#define START (TAG - 2)
#define STOP (TAG - 1)
#define MARGIN 0.03125f   // >> max fp32 rounding slack (~1e-3 at |part|~2000)
#define NSLOT 8

// DPP-based in-register max step: x = max(x, dpp_shifted(x)). old = x, so
// lanes with no valid source keep x (identity for max). All-lane exec required.
#define DPPMAX(x, ctrl) do {                                                   \
    float _t = __int_as_float(__builtin_amdgcn_update_dpp(                     \
        __float_as_int(x), __float_as_int(x), (ctrl), 0xf, 0xf, false));       \
    (x) = fmaxf((x), _t); } while (0)

// Safe lowest-set-bit: preserves low bits for curm != 0 (bit 63 OR only
// matters when curm == 0, where the slot is neutralized via pv = -INF).
#define CTZ_SAFE(curm) ((int)__builtin_ctzll((curm) | 0x8000000000000000ull))

// One block = one batch element = ONE wave (64 lanes); lane owns tags
// j = s*64+lane, s=0..3. ZERO DS ops on the per-step critical path:
//  - pmax via DPP reduce (row_shr 1/2/4/8, row_bcast15/31) + readlane 63
//  - candidate compaction via scalar ballot-walk (SGPR masks, ctz) +
//    v_readlane for part values -> candidate (ic, pv) are SCALAR
//  - trans loads use SGPR base + lane offset + imm offsets
// Exact pruning: rows with part[i] < pmax - (Tmax-Tmin) - MARGIN cannot win
// any column (value or first-occurrence argmax). Surviving arithmetic is
// bit-identical to the reference: (emit + T) + part, strict > ascending i
// (walk order: segment-major, bit-position-minor == ascending i).
__global__ __launch_bounds__(64) void viterbi_wave(
    const float* __restrict__ feats,   // [NB][TT][TAG] f32
    const int*   __restrict__ mask,    // [NB][TT] i32
    const float* __restrict__ trans,   // [TAG][TAG] f32
    float* __restrict__ out)           // [NB] scores ++ [NB][TT] decode (as f32)
{
    __shared__ unsigned int bp2[TT][64];  // [t][lane]: 4 packed bp bytes, byte s = tag s*64+lane
    __shared__ float dec_s[TT];

    const int b    = blockIdx.x;
    const int lane = threadIdx.x;

    const float* __restrict__ fb = feats + (size_t)b * TT * TAG;
    const int*   __restrict__ mb = mask  + (size_t)b * TT;

    // ---- emit prefetch for t=0..2 issued FIRST (hides HBM under prologue) ----
    float e00[4], eA[4], eB[4];
    #pragma unroll
    for (int s = 0; s < 4; ++s) e00[s] = fb[(s << 6) + lane];
    #pragma unroll
    for (int s = 0; s < 4; ++s) eA[s] = fb[TAG + (s << 6) + lane];
    #pragma unroll
    for (int s = 0; s < 4; ++s) eB[s] = fb[2 * TAG + (s << 6) + lane];

    // ---- length = sum(mask) ----
    int lm = 0;
    #pragma unroll
    for (int k = 0; k < 8; ++k) lm += mb[(k << 6) + lane];
    #pragma unroll
    for (int o = 32; o; o >>= 1) lm += __shfl_xor(lm, o);
    const int lastidx = (lm > 0) ? (lm - 1) : 0;
    int mkA = mb[1];
    int mkB = mb[2];

    // ---- global Tmax/Tmin (once; warms L2 with trans) ----
    float tmx = -INFINITY, tmn = INFINITY;
    #pragma unroll 8
    for (int k = lane; k < TAG * TAG / 4; k += 64) {
        float4 v = ((const float4*)trans)[k];
        tmx = fmaxf(tmx, fmaxf(fmaxf(v.x, v.y), fmaxf(v.z, v.w)));
        tmn = fminf(tmn, fminf(fminf(v.x, v.y), fminf(v.z, v.w)));
    }
    #pragma unroll
    for (int o = 32; o; o >>= 1) {
        tmx = fmaxf(tmx, __shfl_xor(tmx, o));
        tmn = fminf(tmn, __shfl_xor(tmn, o));
    }
    const float Wwin = (tmx - tmn) + MARGIN;

    // ---- t = 0 ----
    float m[4], pl[4];
    #pragma unroll
    for (int s = 0; s < 4; ++s) {
        m[s]  = e00[s] + trans[START * TAG + (s << 6) + lane];
        pl[s] = m[s];                      // valid when lastidx == 0
    }

    // ---- forward scan: no barriers, no DS on the critical path ----
    for (int t = 1; t < TT; ++t) {
        float e0[4];
        #pragma unroll
        for (int s = 0; s < 4; ++s) e0[s] = eA[s];
        const int mk = mkA;
        #pragma unroll
        for (int s = 0; s < 4; ++s) eA[s] = eB[s];
        mkA = mkB;

        // pmax via DPP reduce (~15 VALU) -> thr uniform
        float red = fmaxf(fmaxf(m[0], m[1]), fmaxf(m[2], m[3]));
        DPPMAX(red, 0x111);   // row_shr:1
        DPPMAX(red, 0x112);   // row_shr:2
        DPPMAX(red, 0x114);   // row_shr:4
        DPPMAX(red, 0x118);   // row_shr:8
        DPPMAX(red, 0x142);   // row_bcast:15
        DPPMAX(red, 0x143);   // row_bcast:31
        const float pmax = __int_as_float(
            __builtin_amdgcn_readlane(__float_as_int(red), 63));
        const float thr = pmax - Wwin;

        // ballots -> 4 uniform SGPR masks (ascending i = seg-major, bit-minor)
        unsigned long long r0 = __ballot(m[0] >= thr);
        unsigned long long r1 = __ballot(m[1] >= thr);
        unsigned long long r2 = __ballot(m[2] >= thr);
        unsigned long long r3 = __ballot(m[3] >= thr);
        const int ncand = __popcll(r0) + __popcll(r1) + __popcll(r2) + __popcll(r3);

        float nm[4];
        int   bi[4];
        #pragma unroll
        for (int c = 0; c < 4; ++c) { nm[c] = -INFINITY; bi[c] = 0; }

        // ---- batch 1: scalar walk extracts (ic, pv); loads batched ----
        int   ics[NSLOT];
        float pvs[NSLOT];
        #pragma unroll
        for (int k = 0; k < NSLOT; ++k) {
            const bool q0 = (r0 != 0ull), q1 = (r1 != 0ull), q2 = (r2 != 0ull);
            const unsigned long long curm = q0 ? r0 : (q1 ? r1 : (q2 ? r2 : r3));
            const int li = CTZ_SAFE(curm);
            const unsigned long long nxt = curm & (curm - 1ull);
            r0 = q0 ? nxt : r0;
            r1 = (!q0 && q1) ? nxt : r1;
            r2 = (!q0 && !q1 && q2) ? nxt : r2;
            r3 = (!q0 && !q1 && !q2) ? nxt : r3;
            const int pb0 = __builtin_amdgcn_readlane(__float_as_int(m[0]), li);
            const int pb1 = __builtin_amdgcn_readlane(__float_as_int(m[1]), li);
            const int pb2 = __builtin_amdgcn_readlane(__float_as_int(m[2]), li);
            const int pb3 = __builtin_amdgcn_readlane(__float_as_int(m[3]), li);
            const int ps  = q0 ? pb0 : (q1 ? pb1 : (q2 ? pb2 : pb3));
            ics[k] = (q0 ? 0 : (q1 ? 64 : (q2 ? 128 : 192))) + li;
            pvs[k] = (k < ncand) ? __int_as_float(ps) : -INFINITY; // never wins
        }
        float tv[NSLOT][4];
        #pragma unroll
        for (int k = 0; k < NSLOT; ++k) {
            const float* tb = trans + ((size_t)ics[k] << 8) + lane;
            tv[k][0] = tb[0]; tv[k][1] = tb[64]; tv[k][2] = tb[128]; tv[k][3] = tb[192];
        }
        // next-step emit prefetch issued AFTER the tv loads so the compiler's
        // wait for tv doesn't drain these fresh (slow) loads
        const int tp = (t + 2 <= TT - 1) ? (t + 2) : (TT - 1);
        #pragma unroll
        for (int s = 0; s < 4; ++s) eB[s] = fb[(size_t)tp * TAG + (s << 6) + lane];
        mkB = mb[tp];

        #pragma unroll
        for (int k = 0; k < NSLOT; ++k) {
            #pragma unroll
            for (int c = 0; c < 4; ++c) {
                const float cur = (e0[c] + tv[k][c]) + pvs[k];  // exact assoc
                if (cur > nm[c]) { nm[c] = cur; bi[c] = ics[k]; }
            }
        }

        // ---- batch 2 (uniform branch, rare): slots 8..15 ----
        if (ncand > NSLOT) {
            int   ics2[NSLOT];
            float pvs2[NSLOT];
            #pragma unroll
            for (int k = 0; k < NSLOT; ++k) {
                const bool q0 = (r0 != 0ull), q1 = (r1 != 0ull), q2 = (r2 != 0ull);
                const unsigned long long curm = q0 ? r0 : (q1 ? r1 : (q2 ? r2 : r3));
                const int li = CTZ_SAFE(curm);
                const unsigned long long nxt = curm & (curm - 1ull);
                r0 = q0 ? nxt : r0;
                r1 = (!q0 && q1) ? nxt : r1;
                r2 = (!q0 && !q1 && q2) ? nxt : r2;
                r3 = (!q0 && !q1 && !q2) ? nxt : r3;
                const int pb0 = __builtin_amdgcn_readlane(__float_as_int(m[0]), li);
                const int pb1 = __builtin_amdgcn_readlane(__float_as_int(m[1]), li);
                const int pb2 = __builtin_amdgcn_readlane(__float_as_int(m[2]), li);
                const int pb3 = __builtin_amdgcn_readlane(__float_as_int(m[3]), li);
                const int ps  = q0 ? pb0 : (q1 ? pb1 : (q2 ? pb2 : pb3));
                ics2[k] = (q0 ? 0 : (q1 ? 64 : (q2 ? 128 : 192))) + li;
                pvs2[k] = (k + NSLOT < ncand) ? __int_as_float(ps) : -INFINITY;
            }
            float tv2[NSLOT][4];
            #pragma unroll
            for (int k = 0; k < NSLOT; ++k) {
                const float* tb = trans + ((size_t)ics2[k] << 8) + lane;
                tv2[k][0] = tb[0]; tv2[k][1] = tb[64]; tv2[k][2] = tb[128]; tv2[k][3] = tb[192];
            }
            #pragma unroll
            for (int k = 0; k < NSLOT; ++k) {
                #pragma unroll
                for (int c = 0; c < 4; ++c) {
                    const float cur = (e0[c] + tv2[k][c]) + pvs2[k];
                    if (cur > nm[c]) { nm[c] = cur; bi[c] = ics2[k]; }
                }
            }
            // ---- serial tail (ncand > 16): correct, ~never taken ----
            while ((r0 | r1 | r2 | r3) != 0ull) {
                const bool q0 = (r0 != 0ull), q1 = (r1 != 0ull), q2 = (r2 != 0ull);
                const unsigned long long curm = q0 ? r0 : (q1 ? r1 : (q2 ? r2 : r3));
                const int li = (int)__builtin_ctzll(curm);
                const unsigned long long nxt = curm & (curm - 1ull);
                r0 = q0 ? nxt : r0;
                r1 = (!q0 && q1) ? nxt : r1;
                r2 = (!q0 && !q1 && q2) ? nxt : r2;
                r3 = (!q0 && !q1 && !q2) ? nxt : r3;
                const int pb0 = __builtin_amdgcn_readlane(__float_as_int(m[0]), li);
                const int pb1 = __builtin_amdgcn_readlane(__float_as_int(m[1]), li);
                const int pb2 = __builtin_amdgcn_readlane(__float_as_int(m[2]), li);
                const int pb3 = __builtin_amdgcn_readlane(__float_as_int(m[3]), li);
                const int ps  = q0 ? pb0 : (q1 ? pb1 : (q2 ? pb2 : pb3));
                const int ic  = (q0 ? 0 : (q1 ? 64 : (q2 ? 128 : 192))) + li;
                const float pv = __int_as_float(ps);
                const float* tb = trans + ((size_t)ic << 8) + lane;
                #pragma unroll
                for (int c = 0; c < 4; ++c) {
                    const float cur = (e0[c] + tb[c << 6]) + pv;
                    if (cur > nm[c]) { nm[c] = cur; bi[c] = ic; }
                }
            }
        }

        const unsigned int pack = (unsigned)bi[0] | ((unsigned)bi[1] << 8)
                                | ((unsigned)bi[2] << 16) | ((unsigned)bi[3] << 24);
        bp2[t][lane] = (mk > 0) ? pack : 0u;

        #pragma unroll
        for (int c = 0; c < 4; ++c) m[c] = nm[c];
        if (t == lastidx) {
            #pragma unroll
            for (int c = 0; c < 4; ++c) pl[c] = nm[c];
        }
    }

    // ---- stop transition + first-occurrence argmax ----
    float bv; int bj;
    {
        const float fv0 = pl[0] + trans[(size_t)lane         * TAG + STOP];
        const float fv1 = pl[1] + trans[(size_t)(64  + lane) * TAG + STOP];
        const float fv2 = pl[2] + trans[(size_t)(128 + lane) * TAG + STOP];
        const float fv3 = pl[3] + trans[(size_t)(192 + lane) * TAG + STOP];
        bv = fv0; bj = lane;
        if (fv1 > bv) { bv = fv1; bj = 64  + lane; }
        if (fv2 > bv) { bv = fv2; bj = 128 + lane; }
        if (fv3 > bv) { bv = fv3; bj = 192 + lane; }
        #pragma unroll
        for (int o = 32; o; o >>= 1) {
            const float ov = __shfl_xor(bv, o);
            const int   oj = __shfl_xor(bj, o);
            if (ov > bv || (ov == bv && oj < bj)) { bv = ov; bj = oj; }
        }
    }

    // ---- backtrack (lane 0; same-wave LDS ops are in-order vs bp2 writes) ----
    if (lane == 0) {
        out[b] = bv;
        int cur = bj;
        dec_s[TT - 1] = (float)cur;
        const unsigned char* bpb = (const unsigned char*)bp2;
        for (int s = TT - 2; s >= 0; --s) {
            // bp row t=s+1; row lastidx is overwritten with `pointer` (ref)
            cur = (s == lastidx) ? bj
                                 : (int)bpb[((s + 1) << 8) + ((cur & 63) << 2) + (cur >> 6)];
            dec_s[s] = (float)cur;
        }
    }

    // ---- coalesced decode write ----
    float* dec = out + NB + (size_t)b * TT;
    #pragma unroll
    for (int k = 0; k < 8; ++k) dec[(k << 6) + lane] = dec_s[(k << 6) + lane];
}

extern "C" void kernel_launch(void* const* d_in, const int* in_sizes, int n_in,
                              void* d_out, int out_size, void* d_ws, size_t ws_size,
                              hipStream_t stream) {
    const float* feats = (const float*)d_in[0];
    const int*   mask  = (const int*)d_in[1];
    const float* trans = (const float*)d_in[2];
    float* out = (float*)d_out;
    viterbi_wave<<<NB, 64, 0, stream>>>(feats, mask, trans, out);
}

// Round 10
// 1263.931 us; speedup vs baseline: 1.1568x; 1.1568x over previous
//
#include <hip/hip_runtime.h>

#define NB 128
#define TT 512
#define TAG 256
#define START (TAG - 2)
#define STOP (TAG - 1)
#define MARGIN 0.03125f   // >> max fp32 rounding slack (~1e-3 at |part|~2000)
#define NSLOT 8

// DPP-based in-register max step: x = max(x, dpp_shifted(x)). old = x, so
// lanes with no valid source keep x (identity for max). All-lane exec required.
// Canonical GCN wave64 max-reduce; result valid in lane 63. Even if this
// under-estimated pmax, pruning stays EXACT (threshold only gets looser).
#define DPPMAX(x, ctrl) do {                                                   \
    float _t = __int_as_float(__builtin_amdgcn_update_dpp(                     \
        __float_as_int(x), __float_as_int(x), (ctrl), 0xf, 0xf, false));       \
    (x) = fmaxf((x), _t); } while (0)

// Argmax combine: b (later slot / higher i) wins only on STRICT > ->
// preserves the reference's first-occurrence-on-ties semantics.
#define COMB(va, ia, vb, ib) do {                                              \
    const bool _g = ((vb) > (va));                                             \
    (va) = _g ? (vb) : (va); (ia) = _g ? (ib) : (ia); } while (0)

// One block = one batch element = ONE wave (64 lanes); lane owns tags
// j = s*64+lane, s=0..3. Per-step critical path:
//   DPP pmax (~80cyc) -> ballot -> parallel LDS compact (write+broadcast read)
//   -> scalar-base trans loads (one L2 latency) -> depth-3 argmax tree.
// Zero barriers (wave-synchronous; same-wave DS ops are in-order).
// Exact pruning: rows with part[i] < pmax - (Tmax-Tmin) - MARGIN cannot win
// any column (value or first-occurrence argmax). Surviving arithmetic is
// bit-identical to the reference: (emit + T) + part, strict > ascending i.
// SAFETY: any candidate index used for an address is masked &255 (in-bounds
// even for unused/uninitialized slots); pv = -INF makes such slots inert.
__global__ __launch_bounds__(64) void viterbi_wave(
    const float* __restrict__ feats,   // [NB][TT][TAG] f32
    const int*   __restrict__ mask,    // [NB][TT] i32
    const float* __restrict__ trans,   // [TAG][TAG] f32
    float* __restrict__ out)           // [NB] scores ++ [NB][TT] decode (as f32)
{
    __shared__ unsigned int bp2[TT][64];  // [t][lane]: 4 packed bp bytes, byte s = tag s*64+lane
    __shared__ float pcand[TAG];          // compacted candidate part values
    __shared__ int   cand[TAG];           // compacted candidate indices (ascending)
    __shared__ float dec_s[TT];

    const int b    = blockIdx.x;
    const int lane = threadIdx.x;

    const float* __restrict__ fb = feats + (size_t)b * TT * TAG;
    const int*   __restrict__ mb = mask  + (size_t)b * TT;

    // ---- emit prefetch for t=0..2 issued FIRST (hides HBM under prologue) ----
    float e00[4], eA[4], eB[4];
    #pragma unroll
    for (int s = 0; s < 4; ++s) e00[s] = fb[(s << 6) + lane];
    #pragma unroll
    for (int s = 0; s < 4; ++s) eA[s] = fb[TAG + (s << 6) + lane];
    #pragma unroll
    for (int s = 0; s < 4; ++s) eB[s] = fb[2 * TAG + (s << 6) + lane];

    // ---- benign-init candidate buffers (first-step unused slots) ----
    #pragma unroll
    for (int s = 0; s < 4; ++s) { cand[(s << 6) + lane] = 0; pcand[(s << 6) + lane] = -INFINITY; }

    // ---- length = sum(mask) ----
    int lm = 0;
    #pragma unroll
    for (int k = 0; k < 8; ++k) lm += mb[(k << 6) + lane];
    #pragma unroll
    for (int o = 32; o; o >>= 1) lm += __shfl_xor(lm, o);
    const int lastidx = (lm > 0) ? (lm - 1) : 0;
    int mkA = mb[1];
    int mkB = mb[2];

    // ---- global Tmax/Tmin (once; warms L2 with trans) ----
    float tmx = -INFINITY, tmn = INFINITY;
    #pragma unroll 8
    for (int k = lane; k < TAG * TAG / 4; k += 64) {
        float4 v = ((const float4*)trans)[k];
        tmx = fmaxf(tmx, fmaxf(fmaxf(v.x, v.y), fmaxf(v.z, v.w)));
        tmn = fminf(tmn, fminf(fminf(v.x, v.y), fminf(v.z, v.w)));
    }
    #pragma unroll
    for (int o = 32; o; o >>= 1) {
        tmx = fmaxf(tmx, __shfl_xor(tmx, o));
        tmn = fminf(tmn, __shfl_xor(tmn, o));
    }
    const float Wwin = (tmx - tmn) + MARGIN;

    // ---- t = 0 ----
    float m[4], pl[4];
    #pragma unroll
    for (int s = 0; s < 4; ++s) {
        m[s]  = e00[s] + trans[START * TAG + (s << 6) + lane];
        pl[s] = m[s];                      // valid when lastidx == 0
    }

    // ---- forward scan: no barriers, no shfl, parallel LDS compact ----
    for (int t = 1; t < TT; ++t) {
        float e0[4];
        #pragma unroll
        for (int s = 0; s < 4; ++s) e0[s] = eA[s];
        const int mk = mkA;
        #pragma unroll
        for (int s = 0; s < 4; ++s) eA[s] = eB[s];
        mkA = mkB;

        // pmax via DPP reduce -> thr uniform
        float red = fmaxf(fmaxf(m[0], m[1]), fmaxf(m[2], m[3]));
        DPPMAX(red, 0x111);   // row_shr:1
        DPPMAX(red, 0x112);   // row_shr:2
        DPPMAX(red, 0x114);   // row_shr:4
        DPPMAX(red, 0x118);   // row_shr:8
        DPPMAX(red, 0x142);   // row_bcast:15
        DPPMAX(red, 0x143);   // row_bcast:31
        const float pmax = __int_as_float(
            __builtin_amdgcn_readlane(__float_as_int(red), 63));
        const float thr = pmax - Wwin;

        // parallel compaction into LDS, ascending i (seg-major, lane-minor)
        const unsigned long long bal0 = __ballot(m[0] >= thr);
        const unsigned long long bal1 = __ballot(m[1] >= thr);
        const unsigned long long bal2 = __ballot(m[2] >= thr);
        const unsigned long long bal3 = __ballot(m[3] >= thr);
        const int c0 = __popcll(bal0), c1 = __popcll(bal1),
                  c2 = __popcll(bal2), c3 = __popcll(bal3);
        const unsigned long long below = (1ull << lane) - 1ull;
        if (m[0] >= thr) { int r =                __popcll(bal0 & below); cand[r] = lane;       pcand[r] = m[0]; }
        if (m[1] >= thr) { int r = c0 +           __popcll(bal1 & below); cand[r] = 64  + lane; pcand[r] = m[1]; }
        if (m[2] >= thr) { int r = c0 + c1 +      __popcll(bal2 & below); cand[r] = 128 + lane; pcand[r] = m[2]; }
        if (m[3] >= thr) { int r = c0 + c1 + c2 + __popcll(bal3 & below); cand[r] = 192 + lane; pcand[r] = m[3]; }
        const int ncand = c0 + c1 + c2 + c3;     // >= 1 (pmax row qualifies)

        // ---- batch 1: slots 0..7 (broadcast LDS reads; masked addresses) ----
        int   ics[NSLOT];
        float pvs[NSLOT];
        #pragma unroll
        for (int k = 0; k < NSLOT; ++k) {
            // uniform-addr LDS broadcast -> scalar; &255 keeps address legal
            ics[k] = __builtin_amdgcn_readfirstlane(cand[k]) & 255;
            pvs[k] = (k < ncand) ? pcand[k] : -INFINITY;  // unused slot inert
        }
        float tv[NSLOT][4];
        #pragma unroll
        for (int k = 0; k < NSLOT; ++k) {
            const float* tb = trans + ((size_t)ics[k] << 8);
            #pragma unroll
            for (int c = 0; c < 4; ++c) tv[k][c] = tb[lane + (c << 6)];
        }
        // next-step emit prefetch issued AFTER the tv loads so the compiler's
        // wait for tv doesn't drain these fresh (slow) loads
        const int tp = (t + 2 <= TT - 1) ? (t + 2) : (TT - 1);
        #pragma unroll
        for (int s = 0; s < 4; ++s) eB[s] = fb[(size_t)tp * TAG + (s << 6) + lane];
        mkB = mb[tp];

        float nm[4];
        int   bi[4];
        #pragma unroll
        for (int c = 0; c < 4; ++c) {
            float cv[NSLOT]; int ci[NSLOT];
            #pragma unroll
            for (int k = 0; k < NSLOT; ++k) {
                cv[k] = (e0[c] + tv[k][c]) + pvs[k];   // exact association
                ci[k] = ics[k];
            }
            // depth-3 tree, static indexing; ascending slots -> first-occurrence
            #pragma unroll
            for (int st = 1; st < NSLOT; st <<= 1)
                #pragma unroll
                for (int k = 0; k + st < NSLOT; k += (st << 1))
                    COMB(cv[k], ci[k], cv[k + st], ci[k + st]);
            nm[c] = cv[0];
            bi[c] = ci[0];
        }

        // ---- batch 2 (uniform branch, uncommon): slots 8..15 ----
        if (ncand > NSLOT) {
            int   ics2[NSLOT];
            float pvs2[NSLOT];
            #pragma unroll
            for (int k = 0; k < NSLOT; ++k) {
                ics2[k] = __builtin_amdgcn_readfirstlane(cand[NSLOT + k]) & 255;
                pvs2[k] = (NSLOT + k < ncand) ? pcand[NSLOT + k] : -INFINITY;
            }
            float tv2[NSLOT][4];
            #pragma unroll
            for (int k = 0; k < NSLOT; ++k) {
                const float* tb = trans + ((size_t)ics2[k] << 8);
                #pragma unroll
                for (int c = 0; c < 4; ++c) tv2[k][c] = tb[lane + (c << 6)];
            }
            #pragma unroll
            for (int c = 0; c < 4; ++c) {
                float cv[NSLOT]; int ci[NSLOT];
                #pragma unroll
                for (int k = 0; k < NSLOT; ++k) {
                    cv[k] = (e0[c] + tv2[k][c]) + pvs2[k];
                    ci[k] = ics2[k];
                }
                #pragma unroll
                for (int st = 1; st < NSLOT; st <<= 1)
                    #pragma unroll
                    for (int k = 0; k + st < NSLOT; k += (st << 1))
                        COMB(cv[k], ci[k], cv[k + st], ci[k + st]);
                COMB(nm[c], bi[c], cv[0], ci[0]);   // batch1 slots are earlier i
            }
            // ---- serial tail (ncand > 16): correct, ~never taken ----
            for (int k = 2 * NSLOT; k < ncand; ++k) {
                const int   icr = __builtin_amdgcn_readfirstlane(cand[k]) & 255;
                const float pvr = pcand[k];
                const float* tb = trans + ((size_t)icr << 8);
                #pragma unroll
                for (int c = 0; c < 4; ++c) {
                    const float cur = (e0[c] + tb[lane + (c << 6)]) + pvr;
                    COMB(nm[c], bi[c], cur, icr);
                }
            }
        }

        const unsigned int pack = (unsigned)bi[0] | ((unsigned)bi[1] << 8)
                                | ((unsigned)bi[2] << 16) | ((unsigned)bi[3] << 24);
        bp2[t][lane] = (mk > 0) ? pack : 0u;

        #pragma unroll
        for (int c = 0; c < 4; ++c) m[c] = nm[c];
        if (t == lastidx) {
            #pragma unroll
            for (int c = 0; c < 4; ++c) pl[c] = nm[c];
        }
    }

    // ---- stop transition + first-occurrence argmax ----
    float bv; int bj;
    {
        const float fv0 = pl[0] + trans[(size_t)lane         * TAG + STOP];
        const float fv1 = pl[1] + trans[(size_t)(64  + lane) * TAG + STOP];
        const float fv2 = pl[2] + trans[(size_t)(128 + lane) * TAG + STOP];
        const float fv3 = pl[3] + trans[(size_t)(192 + lane) * TAG + STOP];
        bv = fv0; bj = lane;
        if (fv1 > bv) { bv = fv1; bj = 64  + lane; }
        if (fv2 > bv) { bv = fv2; bj = 128 + lane; }
        if (fv3 > bv) { bv = fv3; bj = 192 + lane; }
        #pragma unroll
        for (int o = 32; o; o >>= 1) {
            const float ov = __shfl_xor(bv, o);
            const int   oj = __shfl_xor(bj, o);
            if (ov > bv || (ov == bv && oj < bj)) { bv = ov; bj = oj; }
        }
    }

    // ---- backtrack (lane 0; same-wave LDS ops are in-order vs bp2 writes) ----
    if (lane == 0) {
        out[b] = bv;
        int cur = bj;
        dec_s[TT - 1] = (float)cur;
        const unsigned char* bpb = (const unsigned char*)bp2;
        for (int s = TT - 2; s >= 0; --s) {
            // bp row t=s+1; row lastidx is overwritten with `pointer` (ref)
            cur = (s == lastidx) ? bj
                                 : (int)bpb[((s + 1) << 8) + ((cur & 63) << 2) + (cur >> 6)];
            dec_s[s] = (float)cur;
        }
    }

    // ---- coalesced decode write ----
    float* dec = out + NB + (size_t)b * TT;
    #pragma unroll
    for (int k = 0; k < 8; ++k) dec[(k << 6) + lane] = dec_s[(k << 6) + lane];
}

extern "C" void kernel_launch(void* const* d_in, const int* in_sizes, int n_in,
                              void* d_out, int out_size, void* d_ws, size_t ws_size,
                              hipStream_t stream) {
    const float* feats = (const float*)d_in[0];
    const int*   mask  = (const int*)d_in[1];
    const float* trans = (const float*)d_in[2];
    float* out = (float*)d_out;
    viterbi_wave<<<NB, 64, 0, stream>>>(feats, mask, trans, out);
}

// Round 12
// 1088.724 us; speedup vs baseline: 1.3430x; 1.1609x over previous
//
#include <hip/hip_runtime.h>

#define NB 128
#define TT 512
#define TAG 256
#define START (TAG - 2)
#define STOP (TAG - 1)
#define MARGIN 0.03125f   // >> max fp32 rounding slack (~1e-3 at |part|~2000)
#define NSLOT 8

// DPP-based in-register max step: x = max(x, dpp_shifted(x)). old = x, so
// lanes with no valid source keep x (identity for max). Result in lane 63.
// Validated bit-exact in R10 (absmax 0.0).
#define DPPMAX(x, ctrl) do {                                                   \
    float _t = __int_as_float(__builtin_amdgcn_update_dpp(                     \
        __float_as_int(x), __float_as_int(x), (ctrl), 0xf, 0xf, false));       \
    (x) = fmaxf((x), _t); } while (0)

// Argmax combine: b (later slot / higher i) wins only on STRICT > ->
// preserves the reference's first-occurrence-on-ties semantics.
#define COMB(va, ia, vb, ib) do {                                              \
    const bool _g = ((vb) > (va));                                             \
    (va) = _g ? (vb) : (va); (ia) = _g ? (ib) : (ia); } while (0)

// One block = one batch element = ONE wave (64 lanes). Lane owns CONTIGUOUS
// tags j = 4*lane+c, c=0..3 -> trans row gathers are dwordx4 (8 loads, not
// 32), emit prefetch is one dwordx4. Per-step critical path: DPP pmax ->
// ballots -> parallel LDS compact ({ic,pv} int2 pairs, b64 writes / b128
// reads) -> 8 dwordx4 trans loads (VGPR-uniform addr, NO readfirstlane -
// R8/R10 showed readlane chains cost ~1.6x) -> depth-3 argmax tree.
// Zero barriers; same-wave DS ops are in-order.
// Exact pruning: rows with part[i] < pmax - (Tmax-Tmin) - MARGIN cannot win
// any column (value or first-occurrence argmax). Surviving arithmetic is
// bit-identical to the reference: (emit + T) + part, strict > ascending i
// (compaction rank = ascending j: all lanes l'<l precede lane l, then c asc).
// SAFETY: candidate indices masked &255 before addressing; unused slots get
// pv = -INF (inert in compares).
__global__ __launch_bounds__(64) void viterbi_wave(
    const float* __restrict__ feats,   // [NB][TT][TAG] f32
    const int*   __restrict__ mask,    // [NB][TT] i32
    const float* __restrict__ trans,   // [TAG][TAG] f32
    float* __restrict__ out)           // [NB] scores ++ [NB][TT] decode (as f32)
{
    __shared__ unsigned int bp2[TT][64];       // row t: byte j = bp for tag j
    __shared__ __align__(16) int2 candbuf[TAG];// .x = ic, .y = float bits of part
    __shared__ float dec_s[TT];

    const int b    = blockIdx.x;
    const int lane = threadIdx.x;

    const float* __restrict__ fb = feats + (size_t)b * TT * TAG;
    const int*   __restrict__ mb = mask  + (size_t)b * TT;

    // ---- emit prefetch t=0..2 (one dwordx4 each), issued first ----
    float4 e00 = *(const float4*)(fb + (lane << 2));
    float4 eA  = *(const float4*)(fb + TAG + (lane << 2));
    float4 eB  = *(const float4*)(fb + 2 * TAG + (lane << 2));

    // ---- benign-init candidate buffer (t=1 unused slots) ----
    #pragma unroll
    for (int s = 0; s < 4; ++s)
        candbuf[(s << 6) + lane] = make_int2(0, __float_as_int(-INFINITY));

    // ---- length = sum(mask) ----
    int lm = 0;
    #pragma unroll
    for (int k = 0; k < 8; ++k) lm += mb[(k << 6) + lane];
    #pragma unroll
    for (int o = 32; o; o >>= 1) lm += __shfl_xor(lm, o);
    const int lastidx = (lm > 0) ? (lm - 1) : 0;
    int mkA = mb[1];
    int mkB = mb[2];

    // ---- global Tmax/Tmin (once; warms L2 with trans) ----
    float tmx = -INFINITY, tmn = INFINITY;
    #pragma unroll 8
    for (int k = lane; k < TAG * TAG / 4; k += 64) {
        float4 v = ((const float4*)trans)[k];
        tmx = fmaxf(tmx, fmaxf(fmaxf(v.x, v.y), fmaxf(v.z, v.w)));
        tmn = fminf(tmn, fminf(fminf(v.x, v.y), fminf(v.z, v.w)));
    }
    #pragma unroll
    for (int o = 32; o; o >>= 1) {
        tmx = fmaxf(tmx, __shfl_xor(tmx, o));
        tmn = fminf(tmn, __shfl_xor(tmn, o));
    }
    const float Wwin = (tmx - tmn) + MARGIN;

    const unsigned long long below = (1ull << lane) - 1ull;  // loop-invariant

    // ---- t = 0: m[c] = part[4*lane+c] ----
    float m0, m1, m2, m3, pl0, pl1, pl2, pl3;
    {
        float4 t0 = *(const float4*)(trans + START * TAG + (lane << 2));
        m0 = e00.x + t0.x; m1 = e00.y + t0.y; m2 = e00.z + t0.z; m3 = e00.w + t0.w;
        pl0 = m0; pl1 = m1; pl2 = m2; pl3 = m3;   // valid when lastidx == 0
    }

    // ---- forward scan: no barriers, no readlane-per-slot, no shfl ----
    for (int t = 1; t < TT; ++t) {
        const float4 e0 = eA;
        const int mk = mkA;
        eA = eB; mkA = mkB;

        // pmax via DPP reduce -> single readlane (validated cheap)
        float red = fmaxf(fmaxf(m0, m1), fmaxf(m2, m3));
        DPPMAX(red, 0x111);   // row_shr:1
        DPPMAX(red, 0x112);   // row_shr:2
        DPPMAX(red, 0x114);   // row_shr:4
        DPPMAX(red, 0x118);   // row_shr:8
        DPPMAX(red, 0x142);   // row_bcast:15
        DPPMAX(red, 0x143);   // row_bcast:31
        const float pmax = __int_as_float(
            __builtin_amdgcn_readlane(__float_as_int(red), 63));
        const float thr = pmax - Wwin;

        // flags + ballots; ascending-j rank: all lanes l'<l first, then c asc
        const bool f0 = (m0 >= thr), f1 = (m1 >= thr),
                   f2 = (m2 >= thr), f3 = (m3 >= thr);
        const unsigned long long bal0 = __ballot(f0);
        const unsigned long long bal1 = __ballot(f1);
        const unsigned long long bal2 = __ballot(f2);
        const unsigned long long bal3 = __ballot(f3);
        const int ncand = __popcll(bal0) + __popcll(bal1)
                        + __popcll(bal2) + __popcll(bal3);
        const int base = __popcll(bal0 & below) + __popcll(bal1 & below)
                       + __popcll(bal2 & below) + __popcll(bal3 & below);
        const int j4 = lane << 2;
        if (f0) candbuf[base]                               = make_int2(j4,     __float_as_int(m0));
        if (f1) candbuf[base + (int)f0]                     = make_int2(j4 + 1, __float_as_int(m1));
        if (f2) candbuf[base + (int)f0 + (int)f1]           = make_int2(j4 + 2, __float_as_int(m2));
        if (f3) candbuf[base + (int)f0 + (int)f1 + (int)f2] = make_int2(j4 + 3, __float_as_int(m3));

        // ---- batch 1: slots 0..7 via 4x ds_read_b128 (uniform broadcast) ----
        const int4 p0 = ((const int4*)candbuf)[0];   // slots 0,1
        const int4 p1 = ((const int4*)candbuf)[1];   // slots 2,3
        const int4 p2 = ((const int4*)candbuf)[2];   // slots 4,5
        const int4 p3 = ((const int4*)candbuf)[3];   // slots 6,7
        int ics[NSLOT];
        float pvs[NSLOT];
        ics[0] = p0.x & 255; pvs[0] = (0 < ncand) ? __int_as_float(p0.y) : -INFINITY;
        ics[1] = p0.z & 255; pvs[1] = (1 < ncand) ? __int_as_float(p0.w) : -INFINITY;
        ics[2] = p1.x & 255; pvs[2] = (2 < ncand) ? __int_as_float(p1.y) : -INFINITY;
        ics[3] = p1.z & 255; pvs[3] = (3 < ncand) ? __int_as_float(p1.w) : -INFINITY;
        ics[4] = p2.x & 255; pvs[4] = (4 < ncand) ? __int_as_float(p2.y) : -INFINITY;
        ics[5] = p2.z & 255; pvs[5] = (5 < ncand) ? __int_as_float(p2.w) : -INFINITY;
        ics[6] = p3.x & 255; pvs[6] = (6 < ncand) ? __int_as_float(p3.y) : -INFINITY;
        ics[7] = p3.z & 255; pvs[7] = (7 < ncand) ? __int_as_float(p3.w) : -INFINITY;

        float4 tv[NSLOT];
        #pragma unroll
        for (int k = 0; k < NSLOT; ++k)
            tv[k] = *(const float4*)(trans + ((size_t)ics[k] << 8) + (lane << 2));

        // next-step emit/mask prefetch issued after the tv loads
        const int tp = (t + 2 <= TT - 1) ? (t + 2) : (TT - 1);
        eB  = *(const float4*)(fb + (size_t)tp * TAG + (lane << 2));
        mkB = mb[tp];

        float nm0, nm1, nm2, nm3;
        int   bi0, bi1, bi2, bi3;
        {
            float cv[NSLOT]; int ci[NSLOT];
            #pragma unroll
            for (int k = 0; k < NSLOT; ++k) { cv[k] = (e0.x + tv[k].x) + pvs[k]; ci[k] = ics[k]; }
            #pragma unroll
            for (int st = 1; st < NSLOT; st <<= 1)
                #pragma unroll
                for (int k = 0; k + st < NSLOT; k += (st << 1))
                    COMB(cv[k], ci[k], cv[k + st], ci[k + st]);
            nm0 = cv[0]; bi0 = ci[0];
        }
        {
            float cv[NSLOT]; int ci[NSLOT];
            #pragma unroll
            for (int k = 0; k < NSLOT; ++k) { cv[k] = (e0.y + tv[k].y) + pvs[k]; ci[k] = ics[k]; }
            #pragma unroll
            for (int st = 1; st < NSLOT; st <<= 1)
                #pragma unroll
                for (int k = 0; k + st < NSLOT; k += (st << 1))
                    COMB(cv[k], ci[k], cv[k + st], ci[k + st]);
            nm1 = cv[0]; bi1 = ci[0];
        }
        {
            float cv[NSLOT]; int ci[NSLOT];
            #pragma unroll
            for (int k = 0; k < NSLOT; ++k) { cv[k] = (e0.z + tv[k].z) + pvs[k]; ci[k] = ics[k]; }
            #pragma unroll
            for (int st = 1; st < NSLOT; st <<= 1)
                #pragma unroll
                for (int k = 0; k + st < NSLOT; k += (st << 1))
                    COMB(cv[k], ci[k], cv[k + st], ci[k + st]);
            nm2 = cv[0]; bi2 = ci[0];
        }
        {
            float cv[NSLOT]; int ci[NSLOT];
            #pragma unroll
            for (int k = 0; k < NSLOT; ++k) { cv[k] = (e0.w + tv[k].w) + pvs[k]; ci[k] = ics[k]; }
            #pragma unroll
            for (int st = 1; st < NSLOT; st <<= 1)
                #pragma unroll
                for (int k = 0; k + st < NSLOT; k += (st << 1))
                    COMB(cv[k], ci[k], cv[k + st], ci[k + st]);
            nm3 = cv[0]; bi3 = ci[0];
        }

        // ---- batch 2 (uniform branch, uncommon): slots 8..15 + tail ----
        if (ncand > NSLOT) {
            const int4 q0 = ((const int4*)candbuf)[4];
            const int4 q1 = ((const int4*)candbuf)[5];
            const int4 q2 = ((const int4*)candbuf)[6];
            const int4 q3 = ((const int4*)candbuf)[7];
            int ic2[NSLOT]; float pv2[NSLOT];
            ic2[0] = q0.x & 255; pv2[0] = ( 8 < ncand) ? __int_as_float(q0.y) : -INFINITY;
            ic2[1] = q0.z & 255; pv2[1] = ( 9 < ncand) ? __int_as_float(q0.w) : -INFINITY;
            ic2[2] = q1.x & 255; pv2[2] = (10 < ncand) ? __int_as_float(q1.y) : -INFINITY;
            ic2[3] = q1.z & 255; pv2[3] = (11 < ncand) ? __int_as_float(q1.w) : -INFINITY;
            ic2[4] = q2.x & 255; pv2[4] = (12 < ncand) ? __int_as_float(q2.y) : -INFINITY;
            ic2[5] = q2.z & 255; pv2[5] = (13 < ncand) ? __int_as_float(q2.w) : -INFINITY;
            ic2[6] = q3.x & 255; pv2[6] = (14 < ncand) ? __int_as_float(q3.y) : -INFINITY;
            ic2[7] = q3.z & 255; pv2[7] = (15 < ncand) ? __int_as_float(q3.w) : -INFINITY;
            float4 tw[NSLOT];
            #pragma unroll
            for (int k = 0; k < NSLOT; ++k)
                tw[k] = *(const float4*)(trans + ((size_t)ic2[k] << 8) + (lane << 2));
            #pragma unroll
            for (int k = 0; k < NSLOT; ++k) {
                COMB(nm0, bi0, (e0.x + tw[k].x) + pv2[k], ic2[k]);
                COMB(nm1, bi1, (e0.y + tw[k].y) + pv2[k], ic2[k]);
                COMB(nm2, bi2, (e0.z + tw[k].z) + pv2[k], ic2[k]);
                COMB(nm3, bi3, (e0.w + tw[k].w) + pv2[k], ic2[k]);
            }
            // serial tail (ncand > 16): exact, ~never taken
            for (int k = 2 * NSLOT; k < ncand; ++k) {
                const int2 cp = candbuf[k];
                const int   icr = cp.x & 255;
                const float pvr = __int_as_float(cp.y);
                const float4 tt = *(const float4*)(trans + ((size_t)icr << 8) + (lane << 2));
                COMB(nm0, bi0, (e0.x + tt.x) + pvr, icr);
                COMB(nm1, bi1, (e0.y + tt.y) + pvr, icr);
                COMB(nm2, bi2, (e0.z + tt.z) + pvr, icr);
                COMB(nm3, bi3, (e0.w + tt.w) + pvr, icr);
            }
        }

        const unsigned int pack = (unsigned)bi0 | ((unsigned)bi1 << 8)
                                | ((unsigned)bi2 << 16) | ((unsigned)bi3 << 24);
        bp2[t][lane] = (mk > 0) ? pack : 0u;   // byte j of row t = bp[tag 4l+c]

        m0 = nm0; m1 = nm1; m2 = nm2; m3 = nm3;
        if (t == lastidx) { pl0 = m0; pl1 = m1; pl2 = m2; pl3 = m3; }
    }

    // ---- stop transition + first-occurrence argmax (j = 4*lane+c) ----
    float bv; int bj;
    {
        const int j4 = lane << 2;
        const float fv0 = pl0 + trans[(size_t)(j4    ) * TAG + STOP];
        const float fv1 = pl1 + trans[(size_t)(j4 + 1) * TAG + STOP];
        const float fv2 = pl2 + trans[(size_t)(j4 + 2) * TAG + STOP];
        const float fv3 = pl3 + trans[(size_t)(j4 + 3) * TAG + STOP];
        bv = fv0; bj = j4;
        if (fv1 > bv) { bv = fv1; bj = j4 + 1; }
        if (fv2 > bv) { bv = fv2; bj = j4 + 2; }
        if (fv3 > bv) { bv = fv3; bj = j4 + 3; }
        #pragma unroll
        for (int o = 32; o; o >>= 1) {
            const float ov = __shfl_xor(bv, o);
            const int   oj = __shfl_xor(bj, o);
            if (ov > bv || (ov == bv && oj < bj)) { bv = ov; bj = oj; }
        }
    }

    // ---- backtrack (lane 0; same-wave LDS ops in-order vs bp2 writes) ----
    if (lane == 0) {
        out[b] = bv;
        int cur = bj;
        dec_s[TT - 1] = (float)cur;
        const unsigned char* bpb = (const unsigned char*)bp2;
        for (int s = TT - 2; s >= 0; --s) {
            // bp row t=s+1, byte index = tag; row lastidx overwritten w/ ptr
            cur = (s == lastidx) ? bj : (int)bpb[((s + 1) << 8) + cur];
            dec_s[s] = (float)cur;
        }
    }

    // ---- coalesced decode write ----
    float* dec = out + NB + (size_t)b * TT;
    #pragma unroll
    for (int k = 0; k < 8; ++k) dec[(k << 6) + lane] = dec_s[(k << 6) + lane];
}

extern "C" void kernel_launch(void* const* d_in, const int* in_sizes, int n_in,
                              void* d_out, int out_size, void* d_ws, size_t ws_size,
                              hipStream_t stream) {
    const float* feats = (const float*)d_in[0];
    const int*   mask  = (const int*)d_in[1];
    const float* trans = (const float*)d_in[2];
    float* out = (float*)d_out;
    viterbi_wave<<<NB, 64, 0, stream>>>(feats, mask, trans, out);
}